// Round 15
// baseline (164.280 us; speedup 1.0000x reference)
//
#include <hip/hip_runtime.h>
#include <cstdint>
#include <cstddef>

// CapsuleLayer dynamic routing, MI355X — R15.
// R11 geometry (1024-thr blocks, grid 256) + R13 chunk->XCD swizzle + NEW:
// block's x slice (64b x 16c x 16i) staged ONCE into LDS as f16 (32 KB,
// XOR-swizzled (lb&7)<<4 -> <=2-way conflicts). Per-pair x access = one b128
// LDS read instead of two 16-way-scattered global loads (the pattern common
// to R11-R14, all pinned at ~45 us -> suspected LSU/latency bottleneck).
// Wt fragments stay direct-global (coalesced), reg double-buffered.
// ws: Wt 33,554,432 B | SP 33,554,432 B | v0 262,144 B | v01 262,144 B.

#define CN     2048
#define JN     32
#define UN     16
#define IN_    16
#define CPB    16
#define PAIRS  (CPB/2)
#define NCHUNK (CN/CPB)      // 128
#define NBG    2             // b-groups of 64

#define XS_BYTES 32768                   // 64b x 16c x 16i f16
#define LDS_SZ   (XS_BYTES + 2*4*4*16*4) // + psm = 34816 (static decl below)

typedef _Float16 f16;
typedef _Float16 f16x2 __attribute__((ext_vector_type(2)));
typedef _Float16 f16x4 __attribute__((ext_vector_type(4)));
typedef _Float16 f16x8 __attribute__((ext_vector_type(8)));
typedef __fp16   h16x2 __attribute__((ext_vector_type(2)));
typedef float    f32x4 __attribute__((ext_vector_type(4)));

static __device__ __forceinline__ f16x2 pkrtz(float a, float b) {
    h16x2 r = __builtin_amdgcn_cvt_pkrtz(a, b);
    return __builtin_bit_cast(f16x2, r);
}
static __device__ __forceinline__ float fdot2(f16x2 a, f16x2 b, float c) {
    return __builtin_amdgcn_fdot2(__builtin_bit_cast(h16x2, a),
                                  __builtin_bit_cast(h16x2, b), c, false);
}
struct P2 { f16x2 a, b; };
static __device__ __forceinline__ f16x4 join2(f16x2 a, f16x2 b) {
    P2 p{a, b};
    return __builtin_bit_cast(f16x4, p);
}
struct P4 { f16x4 a, b; };
static __device__ __forceinline__ f16x8 join4(f16x4 a, f16x4 b) {
    P4 p{a, b};
    return __builtin_bit_cast(f16x8, p);
}
static __device__ __forceinline__ f16x8 pk8(const float* w) {
    return join4(join2(pkrtz(w[0],w[1]), pkrtz(w[2],w[3])),
                 join2(pkrtz(w[4],w[5]), pkrtz(w[6],w[7])));
}

// W f32 [c][j][i][u] -> Wt f16 [c][j][u][i]. 2048 blocks x 256 thr.
__global__ __launch_bounds__(256)
void transpose_W(const float* __restrict__ W, f16* __restrict__ Wt)
{
    const int c = blockIdx.x;
    const int t = threadIdx.x;
#pragma unroll
    for (int h = 0; h < 2; ++h) {
        const int s = t + h*256;          // 0..511
        const int j = s >> 4;
        const int u = s & 15;
        const float* src = W + (size_t)c*8192 + j*256 + u;
        float wv[16];
#pragma unroll
        for (int i = 0; i < 16; ++i) wv[i] = src[i*16];
        f16* dst = Wt + (size_t)c*8192 + j*256 + u*16;
        *(f16x8*)dst       = pk8(wv);
        *(f16x8*)(dst + 8) = pk8(wv + 8);
    }
}

template<int ROUTED>
__global__ __launch_bounds__(1024)
void route_kernel(const float* __restrict__ x, const f16* __restrict__ Wt,
                  const float* __restrict__ v01g, float* __restrict__ SP)
{
    __shared__ f16   xs[XS_BYTES/2];   // [lb 64][c 16][i 16], XOR-swizzled
    __shared__ float psm[2*4*4*16];    // [cc 2][btl 4][jq 4][b 16]

    const int tid = threadIdx.x;
    const int l   = tid & 63;
    const int wid = tid >> 6;     // 16 waves
    const int btl = wid & 3;      // b-tile (4 x 16 b)
    const int jq  = wid >> 2;     // j-quarter (8 j's)
    const int g   = l >> 4;
    const int m15 = l & 15;

    // chunk->XCD swizzle: both bg-blocks of a chunk share bid mod 8
    const int bid   = blockIdx.x;
    const int xcd   = bid & 7;
    const int kk    = bid >> 3;           // 0..31
    const int chunk = (kk >> 1) * 8 + xcd;
    const int bg    = kk & 1;

    const int bl    = btl*16 + m15;
    const int bglob = bg*64 + bl;
    const int cbase = chunk * CPB;
    const int jbase = jq * 8;
    const int ccme  = g >> 1;     // lane's c within the pair (K=32 packing)

    // ---- stage x slice (64b x 16c x 16i) -> LDS f16, swizzled ----
    {
        const int lb  = tid >> 4;         // 0..63
        const int seg = tid & 15;         // c index
        const float* src = x + ((size_t)(bg*64 + lb)*CN + cbase + seg)*IN_;
        f32x4 a = *(const f32x4*)src;
        f32x4 b = *(const f32x4*)(src + 4);
        f32x4 c = *(const f32x4*)(src + 8);
        f32x4 d = *(const f32x4*)(src + 12);
        float lo8[8] = {a[0],a[1],a[2],a[3],b[0],b[1],b[2],b[3]};
        float hi8[8] = {c[0],c[1],c[2],c[3],d[0],d[1],d[2],d[3]};
        const int byte0 = lb*512 + seg*32;
        const int sw    = (lb & 7) << 4;
        *(f16x8*)((char*)xs + ((byte0     ) ^ sw)) = pk8(lo8);
        *(f16x8*)((char*)xs + ((byte0 + 16) ^ sw)) = pk8(hi8);
    }

    // v01 -> registers (c-invariant)
    f16x2 vfr[8][2];
    if (ROUTED) {
#pragma unroll
        for (int jj = 0; jj < 8; ++jj) {
            f32x4 vv = *(const f32x4*)(v01g + (size_t)bglob*512 + (jbase+jj)*16 + 4*g);
            vfr[jj][0] = pkrtz(vv[0], vv[1]);
            vfr[jj][1] = pkrtz(vv[2], vv[3]);
        }
    }

    f32x4 acc[8];
#pragma unroll
    for (int jj = 0; jj < 8; ++jj) acc[jj] = (f32x4){0.f,0.f,0.f,0.f};
    const f32x4 zero4 = {0.f,0.f,0.f,0.f};

    __syncthreads();                      // xs ready

    // x LDS read address (per pair p: +32B per c-pair)
    const int xsw = (bl & 7) << 4;
    const int xb0 = bl*512 + ccme*32 + (g&1)*16;

    // ---- register double-buffer of Wt fragments ----
    f16x8 wfr[2][8];
    {
        const f16* wb = Wt + (size_t)(cbase + ccme)*8192 + jbase*256
                        + m15*16 + (g&1)*8;
#pragma unroll
        for (int jj = 0; jj < 8; ++jj)
            wfr[0][jj] = *(const f16x8*)(wb + jj*256);
    }

#pragma unroll
    for (int p = 0; p < PAIRS; ++p) {
        const int cur = p & 1, nxt = cur ^ 1;   // static after full unroll

        if (p + 1 < PAIRS) {
            const f16* wb = Wt + (size_t)(cbase + 2*(p+1) + ccme)*8192 + jbase*256
                            + m15*16 + (g&1)*8;
#pragma unroll
            for (int jj = 0; jj < 8; ++jj)
                wfr[nxt][jj] = *(const f16x8*)(wb + jj*256);
        }

        // x fragment: ONE b128 LDS read
        const f16x8 xq = *(const f16x8*)((const char*)xs + ((xb0 + p*64) ^ xsw));

        float lme[8];
        float myrden = 0.f;
        if (ROUTED) {
            f16x8 xz;
#pragma unroll
            for (int r = 0; r < 8; ++r) xz[r] = (f16)0.f;
            const f16x8 xb0f = (ccme == 0) ? xq : xz;
            const f16x8 xb1f = (ccme == 0) ? xz : xq;

            float summe = 0.f;
#pragma unroll
            for (int jj = 0; jj < 8; ++jj) {
                f32x4 uh0 = __builtin_amdgcn_mfma_f32_16x16x32_f16(wfr[cur][jj], xb0f, zero4, 0,0,0);
                float d0 = fdot2(pkrtz(uh0[0], uh0[1]), vfr[jj][0], 0.f);
                d0       = fdot2(pkrtz(uh0[2], uh0[3]), vfr[jj][1], d0);
                f32x4 uh1 = __builtin_amdgcn_mfma_f32_16x16x32_f16(wfr[cur][jj], xb1f, zero4, 0,0,0);
                float d1 = fdot2(pkrtz(uh1[0], uh1[1]), vfr[jj][0], 0.f);
                d1       = fdot2(pkrtz(uh1[2], uh1[3]), vfr[jj][1], d1);
                float t0 = d0 + __shfl_xor(d0, 16);
                float t1 = d1 + __shfl_xor(d1, 16);
                float sown = (ccme == 0) ? t0 : t1;
                float soth = (ccme == 0) ? t1 : t0;
                float dme  = sown + __shfl_xor(soth, 32);
                float e = __expf(dme);            // no max-sub: |logit| << 88
                summe += e;
                lme[jj] = e;
            }
            if ((l & 31) < 16)
                psm[((ccme*4+btl)*4 + jq)*16 + m15] = summe;
            __syncthreads();                      // psm ready
            {
                const float* pp = psm + (ccme*4+btl)*64 + m15;
                myrden = 1.f / (pp[0] + pp[16] + pp[32] + pp[48]);
            }
            __syncthreads();                      // psm consumed
        }

        // ---- phase B: s_j += c_ij * u_hat (c-pair packed K=32) ----
#pragma unroll
        for (int jj = 0; jj < 8; ++jj) {
            f16x8 bx = xq;
            if (ROUTED) {
                const f16 hsc = (f16)(lme[jj] * myrden);
#pragma unroll
                for (int r = 0; r < 8; ++r) bx[r] = xq[r] * hsc;   // v_pk_mul_f16
            }
            acc[jj] = __builtin_amdgcn_mfma_f32_16x16x32_f16(wfr[cur][jj], bx, acc[jj], 0,0,0);
        }
    }

    // partial s: SP[(bg*128+chunk)*64 + bl][j 32][u 16] f32
    float* dst = SP + (((size_t)(bg*NCHUNK + chunk))*64 + bl)*512;
#pragma unroll
    for (int jj = 0; jj < 8; ++jj)
        *(f32x4*)(dst + (jbase+jj)*16 + 4*g) = acc[jj];
}

// Reduce 128 chunk-partials, squash over J. grid 128 (b), block 512 (tid=j*16+u).
__global__ __launch_bounds__(512)
void squash_kernel(const float* __restrict__ SP, float* __restrict__ v0buf,
                   float* __restrict__ v01buf, float* __restrict__ outp, int mode)
{
    __shared__ float sq[512];
    __shared__ float msqs[16];
    const int tid = threadIdx.x;      // j*16 + u
    const int b   = blockIdx.x;
    const int bg  = b >> 6, blb = b & 63;

    const float* base = SP + ((size_t)bg*NCHUNK*64 + blb)*512 + tid;
    float sum = 0.f;
#pragma unroll 8
    for (int ch = 0; ch < NCHUNK; ++ch) sum += base[(size_t)ch * 64 * 512];
    float s = (mode == 0) ? sum * (1.f/32.f) : sum;   // iter0: c_ij = 1/32 exactly

    sq[tid] = s * s;
    __syncthreads();
    if (tid < 16) {
        float m = 0.f;
#pragma unroll
        for (int j2 = 0; j2 < 32; ++j2) m += sq[j2*16 + tid];
        msqs[tid] = m;
    }
    __syncthreads();
    const float msq = msqs[tid & 15];
    const float mag = sqrtf(msq + 1e-8f);
    const float v   = (msq / (1.f + msq)) * (s / (mag + 1e-8f));
    const size_t idx = (size_t)b*512 + tid;
    if (mode == 0)      { v0buf[idx] = v; v01buf[idx] = v; }
    else if (mode == 1) { v01buf[idx] = v0buf[idx] + v; }   // b2 uses v0+v1
    else                { outp[idx] = v; }
}

extern "C" void kernel_launch(void* const* d_in, const int* in_sizes, int n_in,
                              void* d_out, int out_size, void* d_ws, size_t ws_size,
                              hipStream_t stream)
{
    const float* x = (const float*)d_in[0];
    const float* W = (const float*)d_in[1];

    // ws: Wt (32 MiB f16) | SP (32 MiB f32) | v0 | v01
    f16*   Wt  = (f16*)d_ws;
    float* SP  = (float*)((char*)d_ws + (size_t)33554432);
    float* v0  = (float*)((char*)d_ws + (size_t)33554432 * 2);
    float* v01 = v0 + 65536;
    float* out = (float*)d_out;

    transpose_W<<<2048, 256, 0, stream>>>(W, Wt);

    dim3 grid(256), blk(1024);
    route_kernel<0><<<grid, blk, 0, stream>>>(x, Wt, nullptr, SP);
    squash_kernel  <<<128, 512, 0, stream>>>(SP, v0, v01, out, 0);
    route_kernel<1><<<grid, blk, 0, stream>>>(x, Wt, v01, SP);
    squash_kernel  <<<128, 512, 0, stream>>>(SP, v0, v01, out, 1);
    route_kernel<1><<<grid, blk, 0, stream>>>(x, Wt, v01, SP);
    squash_kernel  <<<128, 512, 0, stream>>>(SP, v0, v01, out, 2);
}

// Round 16
// 141.107 us; speedup vs baseline: 1.1642x; 1.1642x over previous
//
#include <hip/hip_runtime.h>
#include <cstdint>
#include <cstddef>

// CapsuleLayer dynamic routing, MI355X — R16.
// R14 exactly (256-thr 4-wave blocks, software pipeline, ping-pong psm,
// chunk->XCD swizzle, direct-global Wt with reg double-buffer) + ONE change:
// the block's x slice (16b x 16c x 16i) staged once into LDS f16 (8 KB,
// XOR-swizzled) -> per-pair x access is one ds_read_b128 instead of the
// 16-row-scattered global gather common to all ~45us rounds (R11-R14).
// 256-thr blocks chosen deliberately: 1024-thr blocks get a ~60-64 VGPR
// allocation (R11/R15) and spill; 256-thr get 84-92 and don't (R12-R14).
// ws: Wt 33,554,432 B | SP 33,554,432 B | v0 262,144 B | v01 262,144 B.

#define CN     2048
#define JN     32
#define UN     16
#define IN_    16
#define CPB    16
#define PAIRS  (CPB/2)
#define NCHUNK (CN/CPB)      // 128
#define NBG    2             // b-groups of 64

typedef _Float16 f16;
typedef _Float16 f16x2 __attribute__((ext_vector_type(2)));
typedef _Float16 f16x4 __attribute__((ext_vector_type(4)));
typedef _Float16 f16x8 __attribute__((ext_vector_type(8)));
typedef __fp16   h16x2 __attribute__((ext_vector_type(2)));
typedef float    f32x4 __attribute__((ext_vector_type(4)));

static __device__ __forceinline__ f16x2 pkrtz(float a, float b) {
    h16x2 r = __builtin_amdgcn_cvt_pkrtz(a, b);
    return __builtin_bit_cast(f16x2, r);
}
static __device__ __forceinline__ float fdot2(f16x2 a, f16x2 b, float c) {
    return __builtin_amdgcn_fdot2(__builtin_bit_cast(h16x2, a),
                                  __builtin_bit_cast(h16x2, b), c, false);
}
struct P2 { f16x2 a, b; };
static __device__ __forceinline__ f16x4 join2(f16x2 a, f16x2 b) {
    P2 p{a, b};
    return __builtin_bit_cast(f16x4, p);
}
struct P4 { f16x4 a, b; };
static __device__ __forceinline__ f16x8 join4(f16x4 a, f16x4 b) {
    P4 p{a, b};
    return __builtin_bit_cast(f16x8, p);
}
static __device__ __forceinline__ f16x8 pk8(const float* w) {
    return join4(join2(pkrtz(w[0],w[1]), pkrtz(w[2],w[3])),
                 join2(pkrtz(w[4],w[5]), pkrtz(w[6],w[7])));
}

// W f32 [c][j][i][u] -> Wt f16 [c][j][u][i]. 2048 blocks x 256 thr.
__global__ __launch_bounds__(256)
void transpose_W(const float* __restrict__ W, f16* __restrict__ Wt)
{
    const int c = blockIdx.x;
    const int t = threadIdx.x;
#pragma unroll
    for (int h = 0; h < 2; ++h) {
        const int s = t + h*256;          // 0..511
        const int j = s >> 4;
        const int u = s & 15;
        const float* src = W + (size_t)c*8192 + j*256 + u;
        float wv[16];
#pragma unroll
        for (int i = 0; i < 16; ++i) wv[i] = src[i*16];
        f16* dst = Wt + (size_t)c*8192 + j*256 + u*16;
        *(f16x8*)dst       = pk8(wv);
        *(f16x8*)(dst + 8) = pk8(wv + 8);
    }
}

template<int ROUTED>
__global__ __launch_bounds__(256)
void route_kernel(const float* __restrict__ x, const f16* __restrict__ Wt,
                  const float* __restrict__ v01g, float* __restrict__ SP)
{
    __shared__ f16   xs[4096];        // [r 16][c 16][i 16] f16, XOR-swizzled, 8 KB
    __shared__ float psm[2][2*4*16];  // ping-pong [cc 2][jq 4][b 16]

    const int tid = threadIdx.x;
    const int l   = tid & 63;
    const int jq  = tid >> 6;     // 4 waves = 4 j-quarters
    const int g   = l >> 4;
    const int m15 = l & 15;

    // chunk->XCD swizzle: all 8 blocks of a chunk share bid mod 8
    const int bid   = blockIdx.x;
    const int xcd   = bid & 7;
    const int k     = bid >> 3;
    const int chunk = (k >> 3) * 8 + xcd;
    const int idx   = k & 7;
    const int bg    = idx >> 2;
    const int btl   = idx & 3;

    const int bl    = btl*16 + m15;
    const int bglob = bg*64 + bl;
    const int cbase = chunk * CPB;
    const int jbase = jq * 8;
    const int ccme  = g >> 1;

    // ---- stage x slice (16b x 16c x 16i) -> LDS f16, swizzled; coalesced 64B/thr ----
    {
        const int r = tid >> 4;           // b-row 0..15
        const int s = tid & 15;           // c index 0..15
        const float* src = x + ((size_t)(bg*64 + btl*16 + r)*CN + cbase + s)*IN_;
        f32x4 a = *(const f32x4*)src;
        f32x4 b = *(const f32x4*)(src + 4);
        f32x4 c = *(const f32x4*)(src + 8);
        f32x4 d = *(const f32x4*)(src + 12);
        float lo8[8] = {a[0],a[1],a[2],a[3],b[0],b[1],b[2],b[3]};
        float hi8[8] = {c[0],c[1],c[2],c[3],d[0],d[1],d[2],d[3]};
        const int byte0 = r*512 + s*32;
        const int sw    = (r & 7) << 4;
        *(f16x8*)((char*)xs + ((byte0     ) ^ sw)) = pk8(lo8);
        *(f16x8*)((char*)xs + ((byte0 + 16) ^ sw)) = pk8(hi8);
    }

    // v01 -> registers (c-invariant)
    f16x2 vfr[8][2];
    if (ROUTED) {
#pragma unroll
        for (int jj = 0; jj < 8; ++jj) {
            f32x4 vv = *(const f32x4*)(v01g + (size_t)bglob*512 + (jbase+jj)*16 + 4*g);
            vfr[jj][0] = pkrtz(vv[0], vv[1]);
            vfr[jj][1] = pkrtz(vv[2], vv[3]);
        }
    }

    f32x4 acc[8];
#pragma unroll
    for (int jj = 0; jj < 8; ++jj) acc[jj] = (f32x4){0.f,0.f,0.f,0.f};
    const f32x4 zero4 = {0.f,0.f,0.f,0.f};

    __syncthreads();                  // xs ready

    // per-pair x LDS address: row m15, c = 2p+ccme, i-half g&1
    const int xsw   = (m15 & 7) << 4;
    const int xbase = m15*512 + ccme*32 + (g&1)*16;

    f16x8 wfr[2][8];
    f16x8 xq2[2];
    float lme2[2][8];

    auto LOADP = [&](int p) {         // p compile-time after unroll
        const int s = p & 1;
        xq2[s] = *(const f16x8*)((const char*)xs + ((xbase + p*64) ^ xsw));
        const f16* wb = Wt + (size_t)(cbase + 2*p + ccme)*8192 + jbase*256
                        + m15*16 + (g&1)*8;
#pragma unroll
        for (int jj = 0; jj < 8; ++jj)
            wfr[s][jj] = *(const f16x8*)(wb + jj*256);
    };

    auto PHASEA = [&](int p) {        // ROUTED only
        const int s = p & 1;
        const f16x8 xq = xq2[s];
        f16x8 xz;
#pragma unroll
        for (int r = 0; r < 8; ++r) xz[r] = (f16)0.f;
        const f16x8 xb0 = (ccme == 0) ? xq : xz;
        const f16x8 xb1 = (ccme == 0) ? xz : xq;
        float summe = 0.f;
#pragma unroll
        for (int jj = 0; jj < 8; ++jj) {
            f32x4 uh0 = __builtin_amdgcn_mfma_f32_16x16x32_f16(wfr[s][jj], xb0, zero4, 0,0,0);
            float d0 = fdot2(pkrtz(uh0[0], uh0[1]), vfr[jj][0], 0.f);
            d0       = fdot2(pkrtz(uh0[2], uh0[3]), vfr[jj][1], d0);
            f32x4 uh1 = __builtin_amdgcn_mfma_f32_16x16x32_f16(wfr[s][jj], xb1, zero4, 0,0,0);
            float d1 = fdot2(pkrtz(uh1[0], uh1[1]), vfr[jj][0], 0.f);
            d1       = fdot2(pkrtz(uh1[2], uh1[3]), vfr[jj][1], d1);
            float t0 = d0 + __shfl_xor(d0, 16);
            float t1 = d1 + __shfl_xor(d1, 16);
            float sown = (ccme == 0) ? t0 : t1;
            float soth = (ccme == 0) ? t1 : t0;
            float dme  = sown + __shfl_xor(soth, 32);
            float e = __expf(dme);    // no max-sub: |logit| << 88
            summe += e;
            lme2[s][jj] = e;
        }
        if ((l & 31) < 16)
            psm[s][(ccme*4 + jq)*16 + m15] = summe;
    };

    auto PHASEB = [&](int p, float myrden) {
        const int s = p & 1;
        const f16x8 xq = xq2[s];
#pragma unroll
        for (int jj = 0; jj < 8; ++jj) {
            f16x8 bx = xq;
            if (ROUTED) {
                const f16 hsc = (f16)(lme2[s][jj] * myrden);
#pragma unroll
                for (int r = 0; r < 8; ++r) bx[r] = xq[r] * hsc;   // v_pk_mul_f16
            }
            acc[jj] = __builtin_amdgcn_mfma_f32_16x16x32_f16(wfr[s][jj], bx, acc[jj], 0,0,0);
        }
    };

    auto RDEN = [&](int p) -> float {
        const float* pp = &psm[p & 1][ccme*64 + m15];
        return 1.f / (pp[0] + pp[16] + pp[32] + pp[48]);
    };

    // ---- prologue ----
    LOADP(0);
    if (ROUTED) { PHASEA(0); __syncthreads(); }

#pragma unroll
    for (int p = 1; p < PAIRS; ++p) {
        float myrden = 0.f;
        if (ROUTED) myrden = RDEN(p - 1);
        LOADP(p);                     // issue early; B(p-1) covers latency
        PHASEB(p - 1, myrden);
        if (ROUTED) { PHASEA(p); __syncthreads(); }
    }

    // ---- epilogue ----
    {
        float myrden = 0.f;
        if (ROUTED) myrden = RDEN(PAIRS - 1);
        PHASEB(PAIRS - 1, myrden);
    }

    // partial s: SP[(bg*128+chunk)*64 + bl][j 32][u 16] f32
    float* dst = SP + (((size_t)(bg*NCHUNK + chunk))*64 + bl)*512;
#pragma unroll
    for (int jj = 0; jj < 8; ++jj)
        *(f32x4*)(dst + (jbase+jj)*16 + 4*g) = acc[jj];
}

// Reduce 128 chunk-partials, squash over J. grid 128 (b), block 512 (tid=j*16+u).
__global__ __launch_bounds__(512)
void squash_kernel(const float* __restrict__ SP, float* __restrict__ v0buf,
                   float* __restrict__ v01buf, float* __restrict__ outp, int mode)
{
    __shared__ float sq[512];
    __shared__ float msqs[16];
    const int tid = threadIdx.x;      // j*16 + u
    const int b   = blockIdx.x;
    const int bg  = b >> 6, blb = b & 63;

    const float* base = SP + ((size_t)bg*NCHUNK*64 + blb)*512 + tid;
    float sum = 0.f;
#pragma unroll 8
    for (int ch = 0; ch < NCHUNK; ++ch) sum += base[(size_t)ch * 64 * 512];
    float s = (mode == 0) ? sum * (1.f/32.f) : sum;   // iter0: c_ij = 1/32 exactly

    sq[tid] = s * s;
    __syncthreads();
    if (tid < 16) {
        float m = 0.f;
#pragma unroll
        for (int j2 = 0; j2 < 32; ++j2) m += sq[j2*16 + tid];
        msqs[tid] = m;
    }
    __syncthreads();
    const float msq = msqs[tid & 15];
    const float mag = sqrtf(msq + 1e-8f);
    const float v   = (msq / (1.f + msq)) * (s / (mag + 1e-8f));
    const size_t idx = (size_t)b*512 + tid;
    if (mode == 0)      { v0buf[idx] = v; v01buf[idx] = v; }
    else if (mode == 1) { v01buf[idx] = v0buf[idx] + v; }   // b2 uses v0+v1
    else                { outp[idx] = v; }
}

extern "C" void kernel_launch(void* const* d_in, const int* in_sizes, int n_in,
                              void* d_out, int out_size, void* d_ws, size_t ws_size,
                              hipStream_t stream)
{
    const float* x = (const float*)d_in[0];
    const float* W = (const float*)d_in[1];

    // ws: Wt (32 MiB f16) | SP (32 MiB f32) | v0 | v01
    f16*   Wt  = (f16*)d_ws;
    float* SP  = (float*)((char*)d_ws + (size_t)33554432);
    float* v0  = (float*)((char*)d_ws + (size_t)33554432 * 2);
    float* v01 = v0 + 65536;
    float* out = (float*)d_out;

    transpose_W<<<2048, 256, 0, stream>>>(W, Wt);

    dim3 grid(1024), blk(256);
    route_kernel<0><<<grid, blk, 0, stream>>>(x, Wt, nullptr, SP);
    squash_kernel  <<<128, 512, 0, stream>>>(SP, v0, v01, out, 0);
    route_kernel<1><<<grid, blk, 0, stream>>>(x, Wt, v01, SP);
    squash_kernel  <<<128, 512, 0, stream>>>(SP, v0, v01, out, 1);
    route_kernel<1><<<grid, blk, 0, stream>>>(x, Wt, v01, SP);
    squash_kernel  <<<128, 512, 0, stream>>>(SP, v0, v01, out, 2);
}

// Round 17
// 131.644 us; speedup vs baseline: 1.2479x; 1.0719x over previous
//
#include <hip/hip_runtime.h>
#include <cstdint>
#include <cstddef>

// CapsuleLayer dynamic routing, MI355X — R17.
// R16 + occupancy attack: (1) j-span per wave 8 -> 4 (512-thr blocks, 8 waves;
// same 16b x 32j block coverage) halves the big per-thread arrays
// (wfr[2][8]->2][4] saves 32 VGPR) -> more waves/SIMD resident;
// (2) prefetch distance 2: LOADP(p+1) issued after PHASEB(p-1), consumed by
// PHASEA(p+1) -> a full A+barrier+B of latency cover (R16's distance-1 gave
// PHASEA only short PHASEB cover).
// ws: Wt 33,554,432 B | SP 33,554,432 B | v0 262,144 B | v01 262,144 B.

#define CN     2048
#define JN     32
#define UN     16
#define IN_    16
#define CPB    16
#define PAIRS  (CPB/2)
#define NCHUNK (CN/CPB)      // 128
#define NBG    2             // b-groups of 64

typedef _Float16 f16;
typedef _Float16 f16x2 __attribute__((ext_vector_type(2)));
typedef _Float16 f16x4 __attribute__((ext_vector_type(4)));
typedef _Float16 f16x8 __attribute__((ext_vector_type(8)));
typedef __fp16   h16x2 __attribute__((ext_vector_type(2)));
typedef float    f32x4 __attribute__((ext_vector_type(4)));

static __device__ __forceinline__ f16x2 pkrtz(float a, float b) {
    h16x2 r = __builtin_amdgcn_cvt_pkrtz(a, b);
    return __builtin_bit_cast(f16x2, r);
}
static __device__ __forceinline__ float fdot2(f16x2 a, f16x2 b, float c) {
    return __builtin_amdgcn_fdot2(__builtin_bit_cast(h16x2, a),
                                  __builtin_bit_cast(h16x2, b), c, false);
}
struct P2 { f16x2 a, b; };
static __device__ __forceinline__ f16x4 join2(f16x2 a, f16x2 b) {
    P2 p{a, b};
    return __builtin_bit_cast(f16x4, p);
}
struct P4 { f16x4 a, b; };
static __device__ __forceinline__ f16x8 join4(f16x4 a, f16x4 b) {
    P4 p{a, b};
    return __builtin_bit_cast(f16x8, p);
}
static __device__ __forceinline__ f16x8 pk8(const float* w) {
    return join4(join2(pkrtz(w[0],w[1]), pkrtz(w[2],w[3])),
                 join2(pkrtz(w[4],w[5]), pkrtz(w[6],w[7])));
}

// W f32 [c][j][i][u] -> Wt f16 [c][j][u][i]. 2048 blocks x 256 thr.
__global__ __launch_bounds__(256)
void transpose_W(const float* __restrict__ W, f16* __restrict__ Wt)
{
    const int c = blockIdx.x;
    const int t = threadIdx.x;
#pragma unroll
    for (int h = 0; h < 2; ++h) {
        const int s = t + h*256;          // 0..511
        const int j = s >> 4;
        const int u = s & 15;
        const float* src = W + (size_t)c*8192 + j*256 + u;
        float wv[16];
#pragma unroll
        for (int i = 0; i < 16; ++i) wv[i] = src[i*16];
        f16* dst = Wt + (size_t)c*8192 + j*256 + u*16;
        *(f16x8*)dst       = pk8(wv);
        *(f16x8*)(dst + 8) = pk8(wv + 8);
    }
}

template<int ROUTED>
__global__ __launch_bounds__(512)
void route_kernel(const float* __restrict__ x, const f16* __restrict__ Wt,
                  const float* __restrict__ v01g, float* __restrict__ SP)
{
    __shared__ f16   xs[4096];        // [r 16][c 16][i 16] f16, XOR-swizzled, 8 KB
    __shared__ float psm[2][2*8*16];  // ping-pong [cc 2][jg 8][b 16]

    const int tid = threadIdx.x;
    const int l   = tid & 63;
    const int jg  = tid >> 6;     // 8 waves = 8 j-groups of 4
    const int g   = l >> 4;
    const int m15 = l & 15;

    // chunk->XCD swizzle: all 8 blocks of a chunk share bid mod 8
    const int bid   = blockIdx.x;
    const int xcd   = bid & 7;
    const int k     = bid >> 3;
    const int chunk = (k >> 3) * 8 + xcd;
    const int idx   = k & 7;
    const int bg    = idx >> 2;
    const int btl   = idx & 3;

    const int bl    = btl*16 + m15;
    const int bglob = bg*64 + bl;
    const int cbase = chunk * CPB;
    const int jbase = jg * 4;
    const int ccme  = g >> 1;

    // ---- stage x slice (16b x 16c x 16i) -> LDS f16, swizzled ----
    if (tid < 256) {
        const int r = tid >> 4;           // b-row 0..15
        const int s = tid & 15;           // c index 0..15
        const float* src = x + ((size_t)(bg*64 + btl*16 + r)*CN + cbase + s)*IN_;
        f32x4 a = *(const f32x4*)src;
        f32x4 b = *(const f32x4*)(src + 4);
        f32x4 c = *(const f32x4*)(src + 8);
        f32x4 d = *(const f32x4*)(src + 12);
        float lo8[8] = {a[0],a[1],a[2],a[3],b[0],b[1],b[2],b[3]};
        float hi8[8] = {c[0],c[1],c[2],c[3],d[0],d[1],d[2],d[3]};
        const int byte0 = r*512 + s*32;
        const int sw    = (r & 7) << 4;
        *(f16x8*)((char*)xs + ((byte0     ) ^ sw)) = pk8(lo8);
        *(f16x8*)((char*)xs + ((byte0 + 16) ^ sw)) = pk8(hi8);
    }

    // v01 -> registers (c-invariant), 4 j's per wave
    f16x2 vfr[4][2];
    if (ROUTED) {
#pragma unroll
        for (int jj = 0; jj < 4; ++jj) {
            f32x4 vv = *(const f32x4*)(v01g + (size_t)bglob*512 + (jbase+jj)*16 + 4*g);
            vfr[jj][0] = pkrtz(vv[0], vv[1]);
            vfr[jj][1] = pkrtz(vv[2], vv[3]);
        }
    }

    f32x4 acc[4];
#pragma unroll
    for (int jj = 0; jj < 4; ++jj) acc[jj] = (f32x4){0.f,0.f,0.f,0.f};
    const f32x4 zero4 = {0.f,0.f,0.f,0.f};

    __syncthreads();                  // xs ready

    const int xsw   = (m15 & 7) << 4;
    const int xbase = m15*512 + ccme*32 + (g&1)*16;

    f16x8 wfr[2][4];
    f16x8 xq2[2];
    float lme2[2][4];

    auto LOADP = [&](int p) {         // p compile-time after unroll
        const int s = p & 1;
        xq2[s] = *(const f16x8*)((const char*)xs + ((xbase + p*64) ^ xsw));
        const f16* wb = Wt + (size_t)(cbase + 2*p + ccme)*8192 + jbase*256
                        + m15*16 + (g&1)*8;
#pragma unroll
        for (int jj = 0; jj < 4; ++jj)
            wfr[s][jj] = *(const f16x8*)(wb + jj*256);
    };

    auto PHASEA = [&](int p) {        // ROUTED only
        const int s = p & 1;
        const f16x8 xq = xq2[s];
        f16x8 xz;
#pragma unroll
        for (int r = 0; r < 8; ++r) xz[r] = (f16)0.f;
        const f16x8 xb0 = (ccme == 0) ? xq : xz;
        const f16x8 xb1 = (ccme == 0) ? xz : xq;
        float summe = 0.f;
#pragma unroll
        for (int jj = 0; jj < 4; ++jj) {
            f32x4 uh0 = __builtin_amdgcn_mfma_f32_16x16x32_f16(wfr[s][jj], xb0, zero4, 0,0,0);
            float d0 = fdot2(pkrtz(uh0[0], uh0[1]), vfr[jj][0], 0.f);
            d0       = fdot2(pkrtz(uh0[2], uh0[3]), vfr[jj][1], d0);
            f32x4 uh1 = __builtin_amdgcn_mfma_f32_16x16x32_f16(wfr[s][jj], xb1, zero4, 0,0,0);
            float d1 = fdot2(pkrtz(uh1[0], uh1[1]), vfr[jj][0], 0.f);
            d1       = fdot2(pkrtz(uh1[2], uh1[3]), vfr[jj][1], d1);
            float t0 = d0 + __shfl_xor(d0, 16);
            float t1 = d1 + __shfl_xor(d1, 16);
            float sown = (ccme == 0) ? t0 : t1;
            float soth = (ccme == 0) ? t1 : t0;
            float dme  = sown + __shfl_xor(soth, 32);
            float e = __expf(dme);    // no max-sub: |logit| << 88
            summe += e;
            lme2[s][jj] = e;
        }
        if ((l & 31) < 16)
            psm[s][(ccme*8 + jg)*16 + m15] = summe;
    };

    auto PHASEB = [&](int p, float myrden) {
        const int s = p & 1;
        const f16x8 xq = xq2[s];
#pragma unroll
        for (int jj = 0; jj < 4; ++jj) {
            f16x8 bx = xq;
            if (ROUTED) {
                const f16 hsc = (f16)(lme2[s][jj] * myrden);
#pragma unroll
                for (int r = 0; r < 8; ++r) bx[r] = xq[r] * hsc;   // v_pk_mul_f16
            }
            acc[jj] = __builtin_amdgcn_mfma_f32_16x16x32_f16(wfr[s][jj], bx, acc[jj], 0,0,0);
        }
    };

    auto RDEN = [&](int p) -> float {
        const float* pp = &psm[p & 1][ccme*128 + m15];
        float d = 0.f;
#pragma unroll
        for (int q = 0; q < 8; ++q) d += pp[q*16];
        return 1.f / d;
    };

    // ---- prologue: distance-2 prefetch ----
    LOADP(0);
    if (1 < PAIRS) LOADP(1);
    if (ROUTED) { PHASEA(0); __syncthreads(); }

#pragma unroll
    for (int p = 1; p < PAIRS; ++p) {
        float myrden = 0.f;
        if (ROUTED) myrden = RDEN(p - 1);
        PHASEB(p - 1, myrden);        // consumes slot (p-1)&1
        if (p + 1 < PAIRS) LOADP(p + 1);   // refills slot (p+1)&1 == (p-1)&1
        if (ROUTED) { PHASEA(p); __syncthreads(); }
    }

    // ---- epilogue ----
    {
        float myrden = 0.f;
        if (ROUTED) myrden = RDEN(PAIRS - 1);
        PHASEB(PAIRS - 1, myrden);
    }

    // partial s: SP[(bg*128+chunk)*64 + bl][j 32][u 16] f32
    float* dst = SP + (((size_t)(bg*NCHUNK + chunk))*64 + bl)*512;
#pragma unroll
    for (int jj = 0; jj < 4; ++jj)
        *(f32x4*)(dst + (jbase+jj)*16 + 4*g) = acc[jj];
}

// Reduce 128 chunk-partials, squash over J. grid 128 (b), block 512 (tid=j*16+u).
__global__ __launch_bounds__(512)
void squash_kernel(const float* __restrict__ SP, float* __restrict__ v0buf,
                   float* __restrict__ v01buf, float* __restrict__ outp, int mode)
{
    __shared__ float sq[512];
    __shared__ float msqs[16];
    const int tid = threadIdx.x;      // j*16 + u
    const int b   = blockIdx.x;
    const int bg  = b >> 6, blb = b & 63;

    const float* base = SP + ((size_t)bg*NCHUNK*64 + blb)*512 + tid;
    float sum = 0.f;
#pragma unroll 8
    for (int ch = 0; ch < NCHUNK; ++ch) sum += base[(size_t)ch * 64 * 512];
    float s = (mode == 0) ? sum * (1.f/32.f) : sum;   // iter0: c_ij = 1/32 exactly

    sq[tid] = s * s;
    __syncthreads();
    if (tid < 16) {
        float m = 0.f;
#pragma unroll
        for (int j2 = 0; j2 < 32; ++j2) m += sq[j2*16 + tid];
        msqs[tid] = m;
    }
    __syncthreads();
    const float msq = msqs[tid & 15];
    const float mag = sqrtf(msq + 1e-8f);
    const float v   = (msq / (1.f + msq)) * (s / (mag + 1e-8f));
    const size_t idx = (size_t)b*512 + tid;
    if (mode == 0)      { v0buf[idx] = v; v01buf[idx] = v; }
    else if (mode == 1) { v01buf[idx] = v0buf[idx] + v; }   // b2 uses v0+v1
    else                { outp[idx] = v; }
}

extern "C" void kernel_launch(void* const* d_in, const int* in_sizes, int n_in,
                              void* d_out, int out_size, void* d_ws, size_t ws_size,
                              hipStream_t stream)
{
    const float* x = (const float*)d_in[0];
    const float* W = (const float*)d_in[1];

    // ws: Wt (32 MiB f16) | SP (32 MiB f32) | v0 | v01
    f16*   Wt  = (f16*)d_ws;
    float* SP  = (float*)((char*)d_ws + (size_t)33554432);
    float* v0  = (float*)((char*)d_ws + (size_t)33554432 * 2);
    float* v01 = v0 + 65536;
    float* out = (float*)d_out;

    transpose_W<<<2048, 256, 0, stream>>>(W, Wt);

    dim3 grid(1024), blk(512);
    route_kernel<0><<<grid, blk, 0, stream>>>(x, Wt, nullptr, SP);
    squash_kernel  <<<128, 512, 0, stream>>>(SP, v0, v01, out, 0);
    route_kernel<1><<<grid, blk, 0, stream>>>(x, Wt, v01, SP);
    squash_kernel  <<<128, 512, 0, stream>>>(SP, v0, v01, out, 1);
    route_kernel<1><<<grid, blk, 0, stream>>>(x, Wt, v01, SP);
    squash_kernel  <<<128, 512, 0, stream>>>(SP, v0, v01, out, 2);
}

// Round 18
// 118.296 us; speedup vs baseline: 1.3887x; 1.1128x over previous
//
#include <hip/hip_runtime.h>
#include <cstdint>
#include <cstddef>

// CapsuleLayer dynamic routing, MI355X — R18.
// R17 route structure (8-wave 512-thr blocks, distance-2 prefetch, ping-pong
// psm, chunk->XCD swizzle, LDS-staged x, direct-global Wt) with:
//  (1) CPB 16->32: SP halves to 16.7 MB -> squash reads and route SP writes
//      halve (aux kernels were ~29% of total);
//  (2) transpose_W rewritten via padded LDS tile: coalesced f32x4 reads AND
//      coalesced 32B writes (was stride-64B global gather).
// ws: Wt 33,554,432 B | SP 16,777,216 B (slot kept 32 MiB) | v0 | v01.

#define CN     2048
#define JN     32
#define UN     16
#define IN_    16
#define CPB    32
#define PAIRS  (CPB/2)       // 16
#define NCHUNK (CN/CPB)      // 64
#define NBG    2             // b-groups of 64

typedef _Float16 f16;
typedef _Float16 f16x2 __attribute__((ext_vector_type(2)));
typedef _Float16 f16x4 __attribute__((ext_vector_type(4)));
typedef _Float16 f16x8 __attribute__((ext_vector_type(8)));
typedef __fp16   h16x2 __attribute__((ext_vector_type(2)));
typedef float    f32x4 __attribute__((ext_vector_type(4)));

static __device__ __forceinline__ f16x2 pkrtz(float a, float b) {
    h16x2 r = __builtin_amdgcn_cvt_pkrtz(a, b);
    return __builtin_bit_cast(f16x2, r);
}
static __device__ __forceinline__ float fdot2(f16x2 a, f16x2 b, float c) {
    return __builtin_amdgcn_fdot2(__builtin_bit_cast(h16x2, a),
                                  __builtin_bit_cast(h16x2, b), c, false);
}
struct P2 { f16x2 a, b; };
static __device__ __forceinline__ f16x4 join2(f16x2 a, f16x2 b) {
    P2 p{a, b};
    return __builtin_bit_cast(f16x4, p);
}
struct P4 { f16x4 a, b; };
static __device__ __forceinline__ f16x8 join4(f16x4 a, f16x4 b) {
    P4 p{a, b};
    return __builtin_bit_cast(f16x8, p);
}
static __device__ __forceinline__ f16x8 pk8(const float* w) {
    return join4(join2(pkrtz(w[0],w[1]), pkrtz(w[2],w[3])),
                 join2(pkrtz(w[4],w[5]), pkrtz(w[6],w[7])));
}

// W f32 [c][j][i][u] -> Wt f16 [c][j][u][i] via padded LDS tile.
// One c per block, 256 thr. Coalesced reads AND writes; LDS <=2-way conflicts.
#define TJ 328   // j-stride in LDS f32 (8 mod 32 -> 2-way max)
#define TI 20    // i-stride
__global__ __launch_bounds__(256)
void transpose_W(const float* __restrict__ W, f16* __restrict__ Wt)
{
    __shared__ float tile[31*TJ + 15*TI + 16];   // ~42 KB
    const int c = blockIdx.x;
    const int t = threadIdx.x;

    // read phase: 8 x f32x4 coalesced
#pragma unroll
    for (int h = 0; h < 8; ++h) {
        const int o = t*4 + h*1024;          // linear f32 offset in c-slice
        f32x4 v = *(const f32x4*)(W + (size_t)c*8192 + o);
        const int u0 = o & 15, i = (o >> 4) & 15, j = o >> 8;
        float* dst = tile + j*TJ + i*TI + u0;
        dst[0]=v[0]; dst[1]=v[1]; dst[2]=v[2]; dst[3]=v[3];
    }
    __syncthreads();

    // write phase: gather i from LDS (<=2-way), write 32B coalesced
#pragma unroll
    for (int h = 0; h < 2; ++h) {
        const int s = t + h*256;             // 0..511
        const int j = s >> 4, u = s & 15;
        float wv[16];
#pragma unroll
        for (int i = 0; i < 16; ++i) wv[i] = tile[j*TJ + i*TI + u];
        f16* dst = Wt + (size_t)c*8192 + j*256 + u*16;
        *(f16x8*)dst       = pk8(wv);
        *(f16x8*)(dst + 8) = pk8(wv + 8);
    }
}

template<int ROUTED>
__global__ __launch_bounds__(512)
void route_kernel(const float* __restrict__ x, const f16* __restrict__ Wt,
                  const float* __restrict__ v01g, float* __restrict__ SP)
{
    __shared__ f16   xs[8192];        // [r 16][c 32][i 16] f16, XOR-swizzled, 16 KB
    __shared__ float psm[2][2*8*16];  // ping-pong [cc 2][jg 8][b 16]

    const int tid = threadIdx.x;
    const int l   = tid & 63;
    const int jg  = tid >> 6;     // 8 waves = 8 j-groups of 4
    const int g   = l >> 4;
    const int m15 = l & 15;

    // chunk->XCD swizzle: all 8 blocks of a chunk share bid mod 8
    const int bid   = blockIdx.x;
    const int xcd   = bid & 7;
    const int k     = bid >> 3;           // 0..63
    const int chunk = (k >> 3) * 8 + xcd; // 0..63
    const int idx   = k & 7;
    const int bg    = idx >> 2;
    const int btl   = idx & 3;

    const int bl    = btl*16 + m15;
    const int bglob = bg*64 + bl;
    const int cbase = chunk * CPB;
    const int jbase = jg * 4;
    const int ccme  = g >> 1;

    // ---- stage x slice (16b x 32c x 16i) -> LDS f16, swizzled; 64B/thr coalesced ----
    {
        const int r = tid >> 5;           // b-row 0..15
        const int s = tid & 31;           // c index 0..31
        const float* src = x + ((size_t)(bg*64 + btl*16 + r)*CN + cbase + s)*IN_;
        f32x4 a = *(const f32x4*)src;
        f32x4 b = *(const f32x4*)(src + 4);
        f32x4 c = *(const f32x4*)(src + 8);
        f32x4 d = *(const f32x4*)(src + 12);
        float lo8[8] = {a[0],a[1],a[2],a[3],b[0],b[1],b[2],b[3]};
        float hi8[8] = {c[0],c[1],c[2],c[3],d[0],d[1],d[2],d[3]};
        const int byte0 = r*1024 + s*32;
        const int sw    = (r & 7) << 4;
        *(f16x8*)((char*)xs + ((byte0     ) ^ sw)) = pk8(lo8);
        *(f16x8*)((char*)xs + ((byte0 + 16) ^ sw)) = pk8(hi8);
    }

    // v01 -> registers (c-invariant), 4 j's per wave
    f16x2 vfr[4][2];
    if (ROUTED) {
#pragma unroll
        for (int jj = 0; jj < 4; ++jj) {
            f32x4 vv = *(const f32x4*)(v01g + (size_t)bglob*512 + (jbase+jj)*16 + 4*g);
            vfr[jj][0] = pkrtz(vv[0], vv[1]);
            vfr[jj][1] = pkrtz(vv[2], vv[3]);
        }
    }

    f32x4 acc[4];
#pragma unroll
    for (int jj = 0; jj < 4; ++jj) acc[jj] = (f32x4){0.f,0.f,0.f,0.f};
    const f32x4 zero4 = {0.f,0.f,0.f,0.f};

    __syncthreads();                  // xs ready

    const int xsw   = (m15 & 7) << 4;
    const int xbase = m15*1024 + ccme*32 + (g&1)*16;

    f16x8 wfr[2][4];
    f16x8 xq2[2];
    float lme2[2][4];

    auto LOADP = [&](int p) {         // p compile-time after unroll
        const int s = p & 1;
        xq2[s] = *(const f16x8*)((const char*)xs + ((xbase + p*64) ^ xsw));
        const f16* wb = Wt + (size_t)(cbase + 2*p + ccme)*8192 + jbase*256
                        + m15*16 + (g&1)*8;
#pragma unroll
        for (int jj = 0; jj < 4; ++jj)
            wfr[s][jj] = *(const f16x8*)(wb + jj*256);
    };

    auto PHASEA = [&](int p) {        // ROUTED only
        const int s = p & 1;
        const f16x8 xq = xq2[s];
        f16x8 xz;
#pragma unroll
        for (int r = 0; r < 8; ++r) xz[r] = (f16)0.f;
        const f16x8 xb0 = (ccme == 0) ? xq : xz;
        const f16x8 xb1 = (ccme == 0) ? xz : xq;
        float summe = 0.f;
#pragma unroll
        for (int jj = 0; jj < 4; ++jj) {
            f32x4 uh0 = __builtin_amdgcn_mfma_f32_16x16x32_f16(wfr[s][jj], xb0, zero4, 0,0,0);
            float d0 = fdot2(pkrtz(uh0[0], uh0[1]), vfr[jj][0], 0.f);
            d0       = fdot2(pkrtz(uh0[2], uh0[3]), vfr[jj][1], d0);
            f32x4 uh1 = __builtin_amdgcn_mfma_f32_16x16x32_f16(wfr[s][jj], xb1, zero4, 0,0,0);
            float d1 = fdot2(pkrtz(uh1[0], uh1[1]), vfr[jj][0], 0.f);
            d1       = fdot2(pkrtz(uh1[2], uh1[3]), vfr[jj][1], d1);
            float t0 = d0 + __shfl_xor(d0, 16);
            float t1 = d1 + __shfl_xor(d1, 16);
            float sown = (ccme == 0) ? t0 : t1;
            float soth = (ccme == 0) ? t1 : t0;
            float dme  = sown + __shfl_xor(soth, 32);
            float e = __expf(dme);    // no max-sub: |logit| << 88
            summe += e;
            lme2[s][jj] = e;
        }
        if ((l & 31) < 16)
            psm[s][(ccme*8 + jg)*16 + m15] = summe;
    };

    auto PHASEB = [&](int p, float myrden) {
        const int s = p & 1;
        const f16x8 xq = xq2[s];
#pragma unroll
        for (int jj = 0; jj < 4; ++jj) {
            f16x8 bx = xq;
            if (ROUTED) {
                const f16 hsc = (f16)(lme2[s][jj] * myrden);
#pragma unroll
                for (int r = 0; r < 8; ++r) bx[r] = xq[r] * hsc;   // v_pk_mul_f16
            }
            acc[jj] = __builtin_amdgcn_mfma_f32_16x16x32_f16(wfr[s][jj], bx, acc[jj], 0,0,0);
        }
    };

    auto RDEN = [&](int p) -> float {
        const float* pp = &psm[p & 1][ccme*128 + m15];
        float d = 0.f;
#pragma unroll
        for (int q = 0; q < 8; ++q) d += pp[q*16];
        return 1.f / d;
    };

    // ---- prologue: distance-2 prefetch ----
    LOADP(0);
    LOADP(1);
    if (ROUTED) { PHASEA(0); __syncthreads(); }

#pragma unroll
    for (int p = 1; p < PAIRS; ++p) {
        float myrden = 0.f;
        if (ROUTED) myrden = RDEN(p - 1);
        PHASEB(p - 1, myrden);        // consumes slot (p-1)&1
        if (p + 1 < PAIRS) LOADP(p + 1);   // refills slot (p+1)&1 == (p-1)&1
        if (ROUTED) { PHASEA(p); __syncthreads(); }
    }

    // ---- epilogue ----
    {
        float myrden = 0.f;
        if (ROUTED) myrden = RDEN(PAIRS - 1);
        PHASEB(PAIRS - 1, myrden);
    }

    // partial s: SP[(bg*64+chunk)*64 + bl][j 32][u 16] f32
    float* dst = SP + (((size_t)(bg*NCHUNK + chunk))*64 + bl)*512;
#pragma unroll
    for (int jj = 0; jj < 4; ++jj)
        *(f32x4*)(dst + (jbase+jj)*16 + 4*g) = acc[jj];
}

// Reduce 64 chunk-partials, squash over J. grid 128 (b), block 512 (tid=j*16+u).
__global__ __launch_bounds__(512)
void squash_kernel(const float* __restrict__ SP, float* __restrict__ v0buf,
                   float* __restrict__ v01buf, float* __restrict__ outp, int mode)
{
    __shared__ float sq[512];
    __shared__ float msqs[16];
    const int tid = threadIdx.x;      // j*16 + u
    const int b   = blockIdx.x;
    const int bg  = b >> 6, blb = b & 63;

    const float* base = SP + ((size_t)bg*NCHUNK*64 + blb)*512 + tid;
    float sum = 0.f;
#pragma unroll 8
    for (int ch = 0; ch < NCHUNK; ++ch) sum += base[(size_t)ch * 64 * 512];
    float s = (mode == 0) ? sum * (1.f/32.f) : sum;   // iter0: c_ij = 1/32 exactly

    sq[tid] = s * s;
    __syncthreads();
    if (tid < 16) {
        float m = 0.f;
#pragma unroll
        for (int j2 = 0; j2 < 32; ++j2) m += sq[j2*16 + tid];
        msqs[tid] = m;
    }
    __syncthreads();
    const float msq = msqs[tid & 15];
    const float mag = sqrtf(msq + 1e-8f);
    const float v   = (msq / (1.f + msq)) * (s / (mag + 1e-8f));
    const size_t idx = (size_t)b*512 + tid;
    if (mode == 0)      { v0buf[idx] = v; v01buf[idx] = v; }
    else if (mode == 1) { v01buf[idx] = v0buf[idx] + v; }   // b2 uses v0+v1
    else                { outp[idx] = v; }
}

extern "C" void kernel_launch(void* const* d_in, const int* in_sizes, int n_in,
                              void* d_out, int out_size, void* d_ws, size_t ws_size,
                              hipStream_t stream)
{
    const float* x = (const float*)d_in[0];
    const float* W = (const float*)d_in[1];

    // ws: Wt (32 MiB f16) | SP (slot 32 MiB, uses 16) | v0 | v01
    f16*   Wt  = (f16*)d_ws;
    float* SP  = (float*)((char*)d_ws + (size_t)33554432);
    float* v0  = (float*)((char*)d_ws + (size_t)33554432 * 2);
    float* v01 = v0 + 65536;
    float* out = (float*)d_out;

    transpose_W<<<2048, 256, 0, stream>>>(W, Wt);

    dim3 grid(512), blk(512);
    route_kernel<0><<<grid, blk, 0, stream>>>(x, Wt, nullptr, SP);
    squash_kernel  <<<128, 512, 0, stream>>>(SP, v0, v01, out, 0);
    route_kernel<1><<<grid, blk, 0, stream>>>(x, Wt, v01, SP);
    squash_kernel  <<<128, 512, 0, stream>>>(SP, v0, v01, out, 1);
    route_kernel<1><<<grid, blk, 0, stream>>>(x, Wt, v01, SP);
    squash_kernel  <<<128, 512, 0, stream>>>(SP, v0, v01, out, 2);
}

// Round 19
// 115.939 us; speedup vs baseline: 1.4169x; 1.0203x over previous
//
#include <hip/hip_runtime.h>
#include <cstdint>
#include <cstddef>

// CapsuleLayer dynamic routing, MI355X — R19.
// R18 (CPB=32, 8-wave route blocks, distance-2 prefetch, ping-pong psm,
// chunk->XCD swizzle, LDS-staged x, direct-global Wt, LDS transpose) + SP
// partial buffer in f16: route passes write 8.4 MB (was 16.8 f32) and squash
// reads f16x2 vectorized — intermediate traffic halves on both sides.
// Accuracy: partial magnitudes ~O(1-30), f16 quantization adds ~1-3e-3 to s;
// headroom 4.5x on threshold.
// ws: Wt 33,554,432 B | SP16 8,388,608 B | v0 262,144 B | v01 262,144 B.

#define CN     2048
#define JN     32
#define UN     16
#define IN_    16
#define CPB    32
#define PAIRS  (CPB/2)       // 16
#define NCHUNK (CN/CPB)      // 64
#define NBG    2             // b-groups of 64

typedef _Float16 f16;
typedef _Float16 f16x2 __attribute__((ext_vector_type(2)));
typedef _Float16 f16x4 __attribute__((ext_vector_type(4)));
typedef _Float16 f16x8 __attribute__((ext_vector_type(8)));
typedef __fp16   h16x2 __attribute__((ext_vector_type(2)));
typedef float    f32x4 __attribute__((ext_vector_type(4)));

static __device__ __forceinline__ f16x2 pkrtz(float a, float b) {
    h16x2 r = __builtin_amdgcn_cvt_pkrtz(a, b);
    return __builtin_bit_cast(f16x2, r);
}
static __device__ __forceinline__ float fdot2(f16x2 a, f16x2 b, float c) {
    return __builtin_amdgcn_fdot2(__builtin_bit_cast(h16x2, a),
                                  __builtin_bit_cast(h16x2, b), c, false);
}
struct P2 { f16x2 a, b; };
static __device__ __forceinline__ f16x4 join2(f16x2 a, f16x2 b) {
    P2 p{a, b};
    return __builtin_bit_cast(f16x4, p);
}
struct P4 { f16x4 a, b; };
static __device__ __forceinline__ f16x8 join4(f16x4 a, f16x4 b) {
    P4 p{a, b};
    return __builtin_bit_cast(f16x8, p);
}
static __device__ __forceinline__ f16x8 pk8(const float* w) {
    return join4(join2(pkrtz(w[0],w[1]), pkrtz(w[2],w[3])),
                 join2(pkrtz(w[4],w[5]), pkrtz(w[6],w[7])));
}

// W f32 [c][j][i][u] -> Wt f16 [c][j][u][i] via padded LDS tile.
#define TJ 328
#define TI 20
__global__ __launch_bounds__(256)
void transpose_W(const float* __restrict__ W, f16* __restrict__ Wt)
{
    __shared__ float tile[31*TJ + 15*TI + 16];
    const int c = blockIdx.x;
    const int t = threadIdx.x;
#pragma unroll
    for (int h = 0; h < 8; ++h) {
        const int o = t*4 + h*1024;
        f32x4 v = *(const f32x4*)(W + (size_t)c*8192 + o);
        const int u0 = o & 15, i = (o >> 4) & 15, j = o >> 8;
        float* dst = tile + j*TJ + i*TI + u0;
        dst[0]=v[0]; dst[1]=v[1]; dst[2]=v[2]; dst[3]=v[3];
    }
    __syncthreads();
#pragma unroll
    for (int h = 0; h < 2; ++h) {
        const int s = t + h*256;
        const int j = s >> 4, u = s & 15;
        float wv[16];
#pragma unroll
        for (int i = 0; i < 16; ++i) wv[i] = tile[j*TJ + i*TI + u];
        f16* dst = Wt + (size_t)c*8192 + j*256 + u*16;
        *(f16x8*)dst       = pk8(wv);
        *(f16x8*)(dst + 8) = pk8(wv + 8);
    }
}

template<int ROUTED>
__global__ __launch_bounds__(512)
void route_kernel(const float* __restrict__ x, const f16* __restrict__ Wt,
                  const float* __restrict__ v01g, f16* __restrict__ SP16)
{
    __shared__ f16   xs[8192];        // [r 16][c 32][i 16] f16, XOR-swizzled
    __shared__ float psm[2][2*8*16];  // ping-pong [cc 2][jg 8][b 16]

    const int tid = threadIdx.x;
    const int l   = tid & 63;
    const int jg  = tid >> 6;
    const int g   = l >> 4;
    const int m15 = l & 15;

    const int bid   = blockIdx.x;
    const int xcd   = bid & 7;
    const int k     = bid >> 3;
    const int chunk = (k >> 3) * 8 + xcd;
    const int idx   = k & 7;
    const int bg    = idx >> 2;
    const int btl   = idx & 3;

    const int bl    = btl*16 + m15;
    const int bglob = bg*64 + bl;
    const int cbase = chunk * CPB;
    const int jbase = jg * 4;
    const int ccme  = g >> 1;

    // stage x slice (16b x 32c x 16i) -> LDS f16, swizzled
    {
        const int r = tid >> 5;
        const int s = tid & 31;
        const float* src = x + ((size_t)(bg*64 + btl*16 + r)*CN + cbase + s)*IN_;
        f32x4 a = *(const f32x4*)src;
        f32x4 b = *(const f32x4*)(src + 4);
        f32x4 c = *(const f32x4*)(src + 8);
        f32x4 d = *(const f32x4*)(src + 12);
        float lo8[8] = {a[0],a[1],a[2],a[3],b[0],b[1],b[2],b[3]};
        float hi8[8] = {c[0],c[1],c[2],c[3],d[0],d[1],d[2],d[3]};
        const int byte0 = r*1024 + s*32;
        const int sw    = (r & 7) << 4;
        *(f16x8*)((char*)xs + ((byte0     ) ^ sw)) = pk8(lo8);
        *(f16x8*)((char*)xs + ((byte0 + 16) ^ sw)) = pk8(hi8);
    }

    f16x2 vfr[4][2];
    if (ROUTED) {
#pragma unroll
        for (int jj = 0; jj < 4; ++jj) {
            f32x4 vv = *(const f32x4*)(v01g + (size_t)bglob*512 + (jbase+jj)*16 + 4*g);
            vfr[jj][0] = pkrtz(vv[0], vv[1]);
            vfr[jj][1] = pkrtz(vv[2], vv[3]);
        }
    }

    f32x4 acc[4];
#pragma unroll
    for (int jj = 0; jj < 4; ++jj) acc[jj] = (f32x4){0.f,0.f,0.f,0.f};
    const f32x4 zero4 = {0.f,0.f,0.f,0.f};

    __syncthreads();

    const int xsw   = (m15 & 7) << 4;
    const int xbase = m15*1024 + ccme*32 + (g&1)*16;

    f16x8 wfr[2][4];
    f16x8 xq2[2];
    float lme2[2][4];

    auto LOADP = [&](int p) {
        const int s = p & 1;
        xq2[s] = *(const f16x8*)((const char*)xs + ((xbase + p*64) ^ xsw));
        const f16* wb = Wt + (size_t)(cbase + 2*p + ccme)*8192 + jbase*256
                        + m15*16 + (g&1)*8;
#pragma unroll
        for (int jj = 0; jj < 4; ++jj)
            wfr[s][jj] = *(const f16x8*)(wb + jj*256);
    };

    auto PHASEA = [&](int p) {
        const int s = p & 1;
        const f16x8 xq = xq2[s];
        f16x8 xz;
#pragma unroll
        for (int r = 0; r < 8; ++r) xz[r] = (f16)0.f;
        const f16x8 xb0 = (ccme == 0) ? xq : xz;
        const f16x8 xb1 = (ccme == 0) ? xz : xq;
        float summe = 0.f;
#pragma unroll
        for (int jj = 0; jj < 4; ++jj) {
            f32x4 uh0 = __builtin_amdgcn_mfma_f32_16x16x32_f16(wfr[s][jj], xb0, zero4, 0,0,0);
            float d0 = fdot2(pkrtz(uh0[0], uh0[1]), vfr[jj][0], 0.f);
            d0       = fdot2(pkrtz(uh0[2], uh0[3]), vfr[jj][1], d0);
            f32x4 uh1 = __builtin_amdgcn_mfma_f32_16x16x32_f16(wfr[s][jj], xb1, zero4, 0,0,0);
            float d1 = fdot2(pkrtz(uh1[0], uh1[1]), vfr[jj][0], 0.f);
            d1       = fdot2(pkrtz(uh1[2], uh1[3]), vfr[jj][1], d1);
            float t0 = d0 + __shfl_xor(d0, 16);
            float t1 = d1 + __shfl_xor(d1, 16);
            float sown = (ccme == 0) ? t0 : t1;
            float soth = (ccme == 0) ? t1 : t0;
            float dme  = sown + __shfl_xor(soth, 32);
            float e = __expf(dme);    // no max-sub: |logit| << 88
            summe += e;
            lme2[s][jj] = e;
        }
        if ((l & 31) < 16)
            psm[s][(ccme*8 + jg)*16 + m15] = summe;
    };

    auto PHASEB = [&](int p, float myrden) {
        const int s = p & 1;
        const f16x8 xq = xq2[s];
#pragma unroll
        for (int jj = 0; jj < 4; ++jj) {
            f16x8 bx = xq;
            if (ROUTED) {
                const f16 hsc = (f16)(lme2[s][jj] * myrden);
#pragma unroll
                for (int r = 0; r < 8; ++r) bx[r] = xq[r] * hsc;   // v_pk_mul_f16
            }
            acc[jj] = __builtin_amdgcn_mfma_f32_16x16x32_f16(wfr[s][jj], bx, acc[jj], 0,0,0);
        }
    };

    auto RDEN = [&](int p) -> float {
        const float* pp = &psm[p & 1][ccme*128 + m15];
        float d = 0.f;
#pragma unroll
        for (int q = 0; q < 8; ++q) d += pp[q*16];
        return 1.f / d;
    };

    LOADP(0);
    LOADP(1);
    if (ROUTED) { PHASEA(0); __syncthreads(); }

#pragma unroll
    for (int p = 1; p < PAIRS; ++p) {
        float myrden = 0.f;
        if (ROUTED) myrden = RDEN(p - 1);
        PHASEB(p - 1, myrden);
        if (p + 1 < PAIRS) LOADP(p + 1);
        if (ROUTED) { PHASEA(p); __syncthreads(); }
    }
    {
        float myrden = 0.f;
        if (ROUTED) myrden = RDEN(PAIRS - 1);
        PHASEB(PAIRS - 1, myrden);
    }

    // partial s -> f16: SP16[((bg*64+chunk)*64 + bl)*512 + j*16 + 4g]
    f16* dst = SP16 + (((size_t)(bg*NCHUNK + chunk))*64 + bl)*512;
#pragma unroll
    for (int jj = 0; jj < 4; ++jj) {
        f32x4 a = acc[jj];
        *(f16x4*)(dst + (jbase+jj)*16 + 4*g) =
            join2(pkrtz(a[0], a[1]), pkrtz(a[2], a[3]));
    }
}

// Reduce 64 chunk-partials (f16), squash over J. grid 128 (b), block 256
// (tid = j*8 + uh; each thread owns u = 2uh, 2uh+1 -> f16x2 loads).
__global__ __launch_bounds__(256)
void squash_kernel(const f16* __restrict__ SP16, float* __restrict__ v0buf,
                   float* __restrict__ v01buf, float* __restrict__ outp, int mode)
{
    __shared__ float sq[256*2];
    __shared__ float msqs[16];
    const int tid = threadIdx.x;
    const int j   = tid >> 3;
    const int uh  = tid & 7;
    const int b   = blockIdx.x;
    const int bg  = b >> 6, blb = b & 63;

    const f16* base = SP16 + ((size_t)(bg*NCHUNK)*64 + blb)*512 + j*16 + uh*2;
    float s0 = 0.f, s1 = 0.f;
#pragma unroll 8
    for (int ch = 0; ch < NCHUNK; ++ch) {
        f16x2 v = *(const f16x2*)(base + (size_t)ch * 64 * 512);
        s0 += (float)v[0];
        s1 += (float)v[1];
    }
    if (mode == 0) { s0 *= (1.f/32.f); s1 *= (1.f/32.f); }

    sq[tid*2+0] = s0*s0;
    sq[tid*2+1] = s1*s1;
    __syncthreads();
    if (tid < 16) {
        const int u = tid, uq = u >> 1, par = u & 1;
        float m = 0.f;
#pragma unroll
        for (int j2 = 0; j2 < 32; ++j2) m += sq[(j2*8 + uq)*2 + par];
        msqs[u] = m;
    }
    __syncthreads();

    const size_t idx0 = (size_t)b*512 + j*16 + uh*2;
#pragma unroll
    for (int q = 0; q < 2; ++q) {
        const float s   = q ? s1 : s0;
        const float msq = msqs[uh*2 + q];
        const float mag = sqrtf(msq + 1e-8f);
        const float v   = (msq / (1.f + msq)) * (s / (mag + 1e-8f));
        const size_t idx = idx0 + q;
        if (mode == 0)      { v0buf[idx] = v; v01buf[idx] = v; }
        else if (mode == 1) { v01buf[idx] = v0buf[idx] + v; }   // b2 uses v0+v1
        else                { outp[idx] = v; }
    }
}

extern "C" void kernel_launch(void* const* d_in, const int* in_sizes, int n_in,
                              void* d_out, int out_size, void* d_ws, size_t ws_size,
                              hipStream_t stream)
{
    const float* x = (const float*)d_in[0];
    const float* W = (const float*)d_in[1];

    // ws: Wt (32 MiB f16) | SP16 (8 MiB f16) | v0 | v01
    f16*   Wt   = (f16*)d_ws;
    f16*   SP16 = (f16*)((char*)d_ws + (size_t)33554432);
    float* v0   = (float*)((char*)d_ws + (size_t)33554432 + 8388608);
    float* v01  = v0 + 65536;
    float* out  = (float*)d_out;

    transpose_W<<<2048, 256, 0, stream>>>(W, Wt);

    dim3 grid(512), blk(512);
    route_kernel<0><<<grid, blk, 0, stream>>>(x, Wt, nullptr, SP16);
    squash_kernel  <<<128, 256, 0, stream>>>(SP16, v0, v01, out, 0);
    route_kernel<1><<<grid, blk, 0, stream>>>(x, Wt, v01, SP16);
    squash_kernel  <<<128, 256, 0, stream>>>(SP16, v0, v01, out, 1);
    route_kernel<1><<<grid, blk, 0, stream>>>(x, Wt, v01, SP16);
    squash_kernel  <<<128, 256, 0, stream>>>(SP16, v0, v01, out, 2);
}

// Round 20
// 115.927 us; speedup vs baseline: 1.4171x; 1.0001x over previous
//
#include <hip/hip_runtime.h>
#include <cstdint>
#include <cstddef>

// CapsuleLayer dynamic routing, MI355X — R20.
// R19 + ONE change: the per-pair barrier is now {s_waitcnt lgkmcnt(0);
// s_barrier} instead of __syncthreads(). __syncthreads emits s_waitcnt
// vmcnt(0) lgkmcnt(0) -> drained the distance-2 Wt prefetch every pair,
// putting full L2 latency back on the critical path. psm is LDS-only ->
// lgkmcnt(0) is sufficient for barrier semantics; Wt loads stay in flight
// (compiler inserts its own vmcnt before the wfr MFMA uses).
// ws: Wt 33,554,432 B | SP16 8,388,608 B | v0 262,144 B | v01 262,144 B.

#define CN     2048
#define JN     32
#define UN     16
#define IN_    16
#define CPB    32
#define PAIRS  (CPB/2)       // 16
#define NCHUNK (CN/CPB)      // 64
#define NBG    2             // b-groups of 64

typedef _Float16 f16;
typedef _Float16 f16x2 __attribute__((ext_vector_type(2)));
typedef _Float16 f16x4 __attribute__((ext_vector_type(4)));
typedef _Float16 f16x8 __attribute__((ext_vector_type(8)));
typedef __fp16   h16x2 __attribute__((ext_vector_type(2)));
typedef float    f32x4 __attribute__((ext_vector_type(4)));

static __device__ __forceinline__ f16x2 pkrtz(float a, float b) {
    h16x2 r = __builtin_amdgcn_cvt_pkrtz(a, b);
    return __builtin_bit_cast(f16x2, r);
}
static __device__ __forceinline__ float fdot2(f16x2 a, f16x2 b, float c) {
    return __builtin_amdgcn_fdot2(__builtin_bit_cast(h16x2, a),
                                  __builtin_bit_cast(h16x2, b), c, false);
}
struct P2 { f16x2 a, b; };
static __device__ __forceinline__ f16x4 join2(f16x2 a, f16x2 b) {
    P2 p{a, b};
    return __builtin_bit_cast(f16x4, p);
}
struct P4 { f16x4 a, b; };
static __device__ __forceinline__ f16x8 join4(f16x4 a, f16x4 b) {
    P4 p{a, b};
    return __builtin_bit_cast(f16x8, p);
}
static __device__ __forceinline__ f16x8 pk8(const float* w) {
    return join4(join2(pkrtz(w[0],w[1]), pkrtz(w[2],w[3])),
                 join2(pkrtz(w[4],w[5]), pkrtz(w[6],w[7])));
}
// LDS-only barrier: psm/xs visibility needs lgkmcnt, NOT vmcnt -> prefetch
// global loads stay outstanding across the barrier.
static __device__ __forceinline__ void lds_barrier() {
    asm volatile("s_waitcnt lgkmcnt(0)" ::: "memory");
    __builtin_amdgcn_s_barrier();
}

// W f32 [c][j][i][u] -> Wt f16 [c][j][u][i] via padded LDS tile.
#define TJ 328
#define TI 20
__global__ __launch_bounds__(256)
void transpose_W(const float* __restrict__ W, f16* __restrict__ Wt)
{
    __shared__ float tile[31*TJ + 15*TI + 16];
    const int c = blockIdx.x;
    const int t = threadIdx.x;
#pragma unroll
    for (int h = 0; h < 8; ++h) {
        const int o = t*4 + h*1024;
        f32x4 v = *(const f32x4*)(W + (size_t)c*8192 + o);
        const int u0 = o & 15, i = (o >> 4) & 15, j = o >> 8;
        float* dst = tile + j*TJ + i*TI + u0;
        dst[0]=v[0]; dst[1]=v[1]; dst[2]=v[2]; dst[3]=v[3];
    }
    __syncthreads();
#pragma unroll
    for (int h = 0; h < 2; ++h) {
        const int s = t + h*256;
        const int j = s >> 4, u = s & 15;
        float wv[16];
#pragma unroll
        for (int i = 0; i < 16; ++i) wv[i] = tile[j*TJ + i*TI + u];
        f16* dst = Wt + (size_t)c*8192 + j*256 + u*16;
        *(f16x8*)dst       = pk8(wv);
        *(f16x8*)(dst + 8) = pk8(wv + 8);
    }
}

template<int ROUTED>
__global__ __launch_bounds__(512)
void route_kernel(const float* __restrict__ x, const f16* __restrict__ Wt,
                  const float* __restrict__ v01g, f16* __restrict__ SP16)
{
    __shared__ f16   xs[8192];        // [r 16][c 32][i 16] f16, XOR-swizzled
    __shared__ float psm[2][2*8*16];  // ping-pong [cc 2][jg 8][b 16]

    const int tid = threadIdx.x;
    const int l   = tid & 63;
    const int jg  = tid >> 6;
    const int g   = l >> 4;
    const int m15 = l & 15;

    const int bid   = blockIdx.x;
    const int xcd   = bid & 7;
    const int k     = bid >> 3;
    const int chunk = (k >> 3) * 8 + xcd;
    const int idx   = k & 7;
    const int bg    = idx >> 2;
    const int btl   = idx & 3;

    const int bl    = btl*16 + m15;
    const int bglob = bg*64 + bl;
    const int cbase = chunk * CPB;
    const int jbase = jg * 4;
    const int ccme  = g >> 1;

    // stage x slice (16b x 32c x 16i) -> LDS f16, swizzled
    {
        const int r = tid >> 5;
        const int s = tid & 31;
        const float* src = x + ((size_t)(bg*64 + btl*16 + r)*CN + cbase + s)*IN_;
        f32x4 a = *(const f32x4*)src;
        f32x4 b = *(const f32x4*)(src + 4);
        f32x4 c = *(const f32x4*)(src + 8);
        f32x4 d = *(const f32x4*)(src + 12);
        float lo8[8] = {a[0],a[1],a[2],a[3],b[0],b[1],b[2],b[3]};
        float hi8[8] = {c[0],c[1],c[2],c[3],d[0],d[1],d[2],d[3]};
        const int byte0 = r*1024 + s*32;
        const int sw    = (r & 7) << 4;
        *(f16x8*)((char*)xs + ((byte0     ) ^ sw)) = pk8(lo8);
        *(f16x8*)((char*)xs + ((byte0 + 16) ^ sw)) = pk8(hi8);
    }

    f16x2 vfr[4][2];
    if (ROUTED) {
#pragma unroll
        for (int jj = 0; jj < 4; ++jj) {
            f32x4 vv = *(const f32x4*)(v01g + (size_t)bglob*512 + (jbase+jj)*16 + 4*g);
            vfr[jj][0] = pkrtz(vv[0], vv[1]);
            vfr[jj][1] = pkrtz(vv[2], vv[3]);
        }
    }

    f32x4 acc[4];
#pragma unroll
    for (int jj = 0; jj < 4; ++jj) acc[jj] = (f32x4){0.f,0.f,0.f,0.f};
    const f32x4 zero4 = {0.f,0.f,0.f,0.f};

    lds_barrier();                    // xs ready (LDS-only dependency)

    const int xsw   = (m15 & 7) << 4;
    const int xbase = m15*1024 + ccme*32 + (g&1)*16;

    f16x8 wfr[2][4];
    f16x8 xq2[2];
    float lme2[2][4];

    auto LOADP = [&](int p) {
        const int s = p & 1;
        xq2[s] = *(const f16x8*)((const char*)xs + ((xbase + p*64) ^ xsw));
        const f16* wb = Wt + (size_t)(cbase + 2*p + ccme)*8192 + jbase*256
                        + m15*16 + (g&1)*8;
#pragma unroll
        for (int jj = 0; jj < 4; ++jj)
            wfr[s][jj] = *(const f16x8*)(wb + jj*256);
    };

    auto PHASEA = [&](int p) {
        const int s = p & 1;
        const f16x8 xq = xq2[s];
        f16x8 xz;
#pragma unroll
        for (int r = 0; r < 8; ++r) xz[r] = (f16)0.f;
        const f16x8 xb0 = (ccme == 0) ? xq : xz;
        const f16x8 xb1 = (ccme == 0) ? xz : xq;
        float summe = 0.f;
#pragma unroll
        for (int jj = 0; jj < 4; ++jj) {
            f32x4 uh0 = __builtin_amdgcn_mfma_f32_16x16x32_f16(wfr[s][jj], xb0, zero4, 0,0,0);
            float d0 = fdot2(pkrtz(uh0[0], uh0[1]), vfr[jj][0], 0.f);
            d0       = fdot2(pkrtz(uh0[2], uh0[3]), vfr[jj][1], d0);
            f32x4 uh1 = __builtin_amdgcn_mfma_f32_16x16x32_f16(wfr[s][jj], xb1, zero4, 0,0,0);
            float d1 = fdot2(pkrtz(uh1[0], uh1[1]), vfr[jj][0], 0.f);
            d1       = fdot2(pkrtz(uh1[2], uh1[3]), vfr[jj][1], d1);
            float t0 = d0 + __shfl_xor(d0, 16);
            float t1 = d1 + __shfl_xor(d1, 16);
            float sown = (ccme == 0) ? t0 : t1;
            float soth = (ccme == 0) ? t1 : t0;
            float dme  = sown + __shfl_xor(soth, 32);
            float e = __expf(dme);    // no max-sub: |logit| << 88
            summe += e;
            lme2[s][jj] = e;
        }
        if ((l & 31) < 16)
            psm[s][(ccme*8 + jg)*16 + m15] = summe;
    };

    auto PHASEB = [&](int p, float myrden) {
        const int s = p & 1;
        const f16x8 xq = xq2[s];
#pragma unroll
        for (int jj = 0; jj < 4; ++jj) {
            f16x8 bx = xq;
            if (ROUTED) {
                const f16 hsc = (f16)(lme2[s][jj] * myrden);
#pragma unroll
                for (int r = 0; r < 8; ++r) bx[r] = xq[r] * hsc;   // v_pk_mul_f16
            }
            acc[jj] = __builtin_amdgcn_mfma_f32_16x16x32_f16(wfr[s][jj], bx, acc[jj], 0,0,0);
        }
    };

    auto RDEN = [&](int p) -> float {
        const float* pp = &psm[p & 1][ccme*128 + m15];
        float d = 0.f;
#pragma unroll
        for (int q = 0; q < 8; ++q) d += pp[q*16];
        return 1.f / d;
    };

    LOADP(0);
    LOADP(1);
    if (ROUTED) { PHASEA(0); lds_barrier(); }

#pragma unroll
    for (int p = 1; p < PAIRS; ++p) {
        float myrden = 0.f;
        if (ROUTED) myrden = RDEN(p - 1);
        PHASEB(p - 1, myrden);
        if (p + 1 < PAIRS) LOADP(p + 1);
        if (ROUTED) { PHASEA(p); lds_barrier(); }
    }
    {
        float myrden = 0.f;
        if (ROUTED) myrden = RDEN(PAIRS - 1);
        PHASEB(PAIRS - 1, myrden);
    }

    // partial s -> f16: SP16[((bg*64+chunk)*64 + bl)*512 + j*16 + 4g]
    f16* dst = SP16 + (((size_t)(bg*NCHUNK + chunk))*64 + bl)*512;
#pragma unroll
    for (int jj = 0; jj < 4; ++jj) {
        f32x4 a = acc[jj];
        *(f16x4*)(dst + (jbase+jj)*16 + 4*g) =
            join2(pkrtz(a[0], a[1]), pkrtz(a[2], a[3]));
    }
}

// Reduce 64 chunk-partials (f16), squash over J. grid 128 (b), block 256.
__global__ __launch_bounds__(256)
void squash_kernel(const f16* __restrict__ SP16, float* __restrict__ v0buf,
                   float* __restrict__ v01buf, float* __restrict__ outp, int mode)
{
    __shared__ float sq[256*2];
    __shared__ float msqs[16];
    const int tid = threadIdx.x;
    const int j   = tid >> 3;
    const int uh  = tid & 7;
    const int b   = blockIdx.x;
    const int bg  = b >> 6, blb = b & 63;

    const f16* base = SP16 + ((size_t)(bg*NCHUNK)*64 + blb)*512 + j*16 + uh*2;
    float s0 = 0.f, s1 = 0.f;
#pragma unroll 8
    for (int ch = 0; ch < NCHUNK; ++ch) {
        f16x2 v = *(const f16x2*)(base + (size_t)ch * 64 * 512);
        s0 += (float)v[0];
        s1 += (float)v[1];
    }
    if (mode == 0) { s0 *= (1.f/32.f); s1 *= (1.f/32.f); }

    sq[tid*2+0] = s0*s0;
    sq[tid*2+1] = s1*s1;
    __syncthreads();
    if (tid < 16) {
        const int u = tid, uq = u >> 1, par = u & 1;
        float m = 0.f;
#pragma unroll
        for (int j2 = 0; j2 < 32; ++j2) m += sq[(j2*8 + uq)*2 + par];
        msqs[u] = m;
    }
    __syncthreads();

    const size_t idx0 = (size_t)b*512 + j*16 + uh*2;
#pragma unroll
    for (int q = 0; q < 2; ++q) {
        const float s   = q ? s1 : s0;
        const float msq = msqs[uh*2 + q];
        const float mag = sqrtf(msq + 1e-8f);
        const float v   = (msq / (1.f + msq)) * (s / (mag + 1e-8f));
        const size_t idx = idx0 + q;
        if (mode == 0)      { v0buf[idx] = v; v01buf[idx] = v; }
        else if (mode == 1) { v01buf[idx] = v0buf[idx] + v; }   // b2 uses v0+v1
        else                { outp[idx] = v; }
    }
}

extern "C" void kernel_launch(void* const* d_in, const int* in_sizes, int n_in,
                              void* d_out, int out_size, void* d_ws, size_t ws_size,
                              hipStream_t stream)
{
    const float* x = (const float*)d_in[0];
    const float* W = (const float*)d_in[1];

    // ws: Wt (32 MiB f16) | SP16 (8 MiB f16) | v0 | v01
    f16*   Wt   = (f16*)d_ws;
    f16*   SP16 = (f16*)((char*)d_ws + (size_t)33554432);
    float* v0   = (float*)((char*)d_ws + (size_t)33554432 + 8388608);
    float* v01  = v0 + 65536;
    float* out  = (float*)d_out;

    transpose_W<<<2048, 256, 0, stream>>>(W, Wt);

    dim3 grid(512), blk(512);
    route_kernel<0><<<grid, blk, 0, stream>>>(x, Wt, nullptr, SP16);
    squash_kernel  <<<128, 256, 0, stream>>>(SP16, v0, v01, out, 0);
    route_kernel<1><<<grid, blk, 0, stream>>>(x, Wt, v01, SP16);
    squash_kernel  <<<128, 256, 0, stream>>>(SP16, v0, v01, out, 1);
    route_kernel<1><<<grid, blk, 0, stream>>>(x, Wt, v01, SP16);
    squash_kernel  <<<128, 256, 0, stream>>>(SP16, v0, v01, out, 2);
}